// Round 10
// baseline (47.433 us; speedup 1.0000x reference)
//
#include <hip/hip_runtime.h>
#include <hip/hip_bf16.h>
#include <cstdint>
#include <cstddef>

#define B_ 8
#define T_ 2048
#define E_ 1024
#define D_ 64

typedef __attribute__((ext_vector_type(8))) short bf16x8;
typedef __attribute__((ext_vector_type(4))) float f32x4;
typedef __attribute__((ext_vector_type(16))) float f32x16;
typedef __attribute__((ext_vector_type(4))) unsigned short u16x4;

#define QSCALE 0.1803368801111204f  // 0.125 * log2(e)

__device__ __forceinline__ short f2bf(float f){
    __hip_bfloat16 h = __float2bfloat16(f);
    return *reinterpret_cast<short*>(&h);
}

__device__ __forceinline__ bf16x8 cvt8v(const f32x4 a, const f32x4 b){
    bf16x8 r;
    r[0]=f2bf(a[0]); r[1]=f2bf(a[1]); r[2]=f2bf(a[2]); r[3]=f2bf(a[3]);
    r[4]=f2bf(b[0]); r[5]=f2bf(b[1]); r[6]=f2bf(b[2]); r[7]=f2bf(b[3]);
    return r;
}

// ---------- W -> MFMA-fragment-linear layout (unchanged) ----------
__global__ __launch_bounds__(256) void wconv_kernel(
    const float* __restrict__ Wq, const float* __restrict__ Wk,
    const float* __restrict__ Wv, __hip_bfloat16* __restrict__ Wfrag)
{
    const int g = blockIdx.x*256 + threadIdx.x;   // [0, 24576)
    const int l = g & 63;
    const int ntg = (g >> 6) % 6;
    const int cg = g / 384;
    const int n = ntg*32 + (l & 31);
    const int m = n >> 6;
    const int ncol = n & 63;
    const float* W = (m==0) ? Wq : (m==1) ? Wk : Wv;
    const float sc = (m==0) ? QSCALE : 1.0f;
    const int k0 = cg*16 + (l>>5)*8;
    bf16x8 r;
    #pragma unroll
    for (int j=0;j<8;++j)
        r[j] = f2bf(W[(size_t)(k0+j)*64 + ncol] * sc);
    *reinterpret_cast<bf16x8*>(Wfrag + (size_t)g*8) = r;
}

// ---------- QKV projection v5: 256B LDS rows, dual acc chains, 7 barriers, frag-direct epilogue ----------
__global__ __launch_bounds__(384, 3) void proj_kernel(
    const float* __restrict__ x, const __hip_bfloat16* __restrict__ Wfrag,
    __hip_bfloat16* __restrict__ Qfrag, __hip_bfloat16* __restrict__ Kfrag,
    __hip_bfloat16* __restrict__ Vfrag)
{
    __shared__ __align__(16) unsigned short xs[2][32*128];  // 16 KB dbuf: 32 rows x 256 B
    __shared__ float vt[32*65];                             // 8.3 KB transpose scratch
    const int tid = threadIdx.x;
    const int w = tid>>6, l = tid&63;
    const int l31 = l&31, kg = l>>5;
    const int l15 = l&15, lg = l>>4;
    const float* xp = x + (size_t)blockIdx.x*32*E_;

    f32x16 accE, accO;
    #pragma unroll
    for (int j=0;j<16;++j){ accE[j]=0.f; accO[j]=0.f; }

    const bf16x8* Wfp = reinterpret_cast<const bf16x8*>(Wfrag);

    bf16x8 btA[8], btB[8];
    #pragma unroll
    for (int c=0;c<8;++c)
        btA[c] = Wfp[(size_t)((c*6 + w)*64 + l)];

    const int srow = tid>>4, sg = tid&15;   // stager: 16 lanes cover one row's 128-elem slice

    // prologue: stage phase 0 (two passes: rows 0-15, 16-31)
    if (tid < 256){
        #pragma unroll
        for (int pass=0; pass<2; ++pass){
            const int row = pass*16 + srow;
            f32x4 v0 = *reinterpret_cast<const f32x4*>(xp + (size_t)row*E_ + sg*8);
            f32x4 v1 = *reinterpret_cast<const f32x4*>(xp + (size_t)row*E_ + sg*8 + 4);
            *reinterpret_cast<bf16x8*>((char*)&xs[0][0] + row*256 + ((sg ^ (row&15))<<4)) = cvt8v(v0, v1);
        }
    }
    __syncthreads();

#define PPHASE(P, BC, BN)                                                      \
    {                                                                          \
        const int p = (P);                                                     \
        if (p+1 < 8){                                                          \
            _Pragma("unroll")                                                  \
            for (int c=0;c<8;++c)                                              \
                BN[c] = Wfp[(size_t)((((p+1)*8+c)*6 + w)*64 + l)];             \
        }                                                                      \
        f32x4 xa0a, xa0b, xa1a, xa1b;                                          \
        if (p+1 < 8 && tid < 256){                                             \
            xa0a = *reinterpret_cast<const f32x4*>(xp + (size_t)srow*E_ + (p+1)*128 + sg*8);        \
            xa0b = *reinterpret_cast<const f32x4*>(xp + (size_t)srow*E_ + (p+1)*128 + sg*8 + 4);    \
            xa1a = *reinterpret_cast<const f32x4*>(xp + (size_t)(16+srow)*E_ + (p+1)*128 + sg*8);   \
            xa1b = *reinterpret_cast<const f32x4*>(xp + (size_t)(16+srow)*E_ + (p+1)*128 + sg*8 + 4);\
        }                                                                      \
        const char* xb = (const char*)&xs[p&1][0];                             \
        _Pragma("unroll")                                                      \
        for (int c=0;c<8;++c){                                                 \
            bf16x8 af = *reinterpret_cast<const bf16x8*>(xb + l31*256 + (((c*2+kg) ^ (l31&15))<<4)); \
            if (c & 1) accO = __builtin_amdgcn_mfma_f32_32x32x16_bf16(af, BC[c], accO, 0,0,0);       \
            else       accE = __builtin_amdgcn_mfma_f32_32x32x16_bf16(af, BC[c], accE, 0,0,0);       \
        }                                                                      \
        if (p+1 < 8){                                                          \
            if (tid < 256){                                                    \
                char* xd = (char*)&xs[(p+1)&1][0];                             \
                *reinterpret_cast<bf16x8*>(xd + srow*256 + ((sg ^ (srow&15))<<4)) = cvt8v(xa0a, xa0b);          \
                *reinterpret_cast<bf16x8*>(xd + (16+srow)*256 + ((sg ^ ((16+srow)&15))<<4)) = cvt8v(xa1a, xa1b);\
            }                                                                  \
            __syncthreads();                                                   \
        }                                                                      \
    }

    for (int p2=0; p2<4; ++p2){
        PPHASE(2*p2,   btA, btB)
        PPHASE(2*p2+1, btB, btA)
    }
#undef PPHASE

    float accv[16];
    #pragma unroll
    for (int j=0;j<16;++j) accv[j] = accE[j] + accO[j];

    // ---- epilogue: direct frag-layout writes via vt transpose ----
    const int q = blockIdx.x;
    const int b = q >> 6;
    const int q63 = q & 63;
    const int t  = q63 >> 1;

    const int sl = tid;
    const int su_w = (sl>>7)&1, ks_w = (sl>>6)&1, lw = sl&63;
    const int lw15 = lw&15, lwg = lw>>4;

    // Q (waves 0,1)
    __syncthreads();
    if (w < 2){
        const int col = (w&1)*32 + l31;
        #pragma unroll
        for (int reg=0; reg<16; ++reg){
            const int mr = (reg&3) + 8*(reg>>2) + 4*kg;
            vt[mr*65 + col] = accv[reg];
        }
    }
    __syncthreads();
    if (sl < 256){
        f32x4 a0, a1;
        #pragma unroll
        for (int j=0;j<4;++j) a0[j] = vt[(su_w*16+lw15)*65 + ks_w*32 + lwg*8 + j];
        #pragma unroll
        for (int j=0;j<4;++j) a1[j] = vt[(su_w*16+lw15)*65 + ks_w*32 + lwg*8 + 4 + j];
        const size_t gi = ((size_t)(b*128 + 2*q63 + su_w)*2 + ks_w)*64 + lw;
        *reinterpret_cast<bf16x8*>(Qfrag + gi*8) = cvt8v(a0, a1);
    }
    // K (waves 2,3)
    __syncthreads();
    if (w >= 2 && w < 4){
        const int col = (w&1)*32 + l31;
        #pragma unroll
        for (int reg=0; reg<16; ++reg){
            const int mr = (reg&3) + 8*(reg>>2) + 4*kg;
            vt[mr*65 + col] = accv[reg];
        }
    }
    __syncthreads();
    if (sl < 256){
        f32x4 a0, a1;
        #pragma unroll
        for (int j=0;j<4;++j) a0[j] = vt[(su_w*16+lw15)*65 + ks_w*32 + lwg*8 + j];
        #pragma unroll
        for (int j=0;j<4;++j) a1[j] = vt[(su_w*16+lw15)*65 + ks_w*32 + lwg*8 + 4 + j];
        const int nt = (q&1)*2 + su_w;
        const size_t gi = (((size_t)(b*32 + t)*4 + nt)*2 + ks_w)*64 + lw;
        *reinterpret_cast<bf16x8*>(Kfrag + gi*8) = cvt8v(a0, a1);
    }
    // V (waves 4,5)
    __syncthreads();
    if (w >= 4){
        const int col = (w&1)*32 + l31;
        #pragma unroll
        for (int reg=0; reg<16; ++reg){
            const int mr = (reg&3) + 8*(reg>>2) + 4*kg;
            vt[mr*65 + col] = accv[reg];
        }
    }
    __syncthreads();
    if (sl < 256){
        const int dt = sl>>6;
        bf16x8 pk;
        #pragma unroll
        for (int j=0;j<8;++j)
            pk[j] = f2bf(vt[(lwg*8+j)*65 + dt*16 + lw15]);
        const size_t gi = (((size_t)(b*32 + t)*4 + dt)*2 + (q&1))*64 + lw;
        *reinterpret_cast<bf16x8*>(Vfrag + gi*8) = pk;
    }
}

// ---------- flash attention v6: shfl-free softmax fast path, deferred l-reduction ----------
__global__ __launch_bounds__(256, 2) void fattn_kernel(
    const __hip_bfloat16* __restrict__ Qfrag, const __hip_bfloat16* __restrict__ Kfrag,
    const __hip_bfloat16* __restrict__ Vfrag, float* __restrict__ out)
{
    __shared__ __align__(16) unsigned short Pl[4][16*64];
    __shared__ float Morg[4][2][16];
    __shared__ float Lorg[4][2][64];        // per-lane l partials
    __shared__ __align__(16) float Oorg[4][2][16*64];

    const int tid = threadIdx.x;
    const int w = tid>>6, l = tid&63;
    const int l15 = l&15, lg = l>>4;

    const int b = blockIdx.x & 7;
    const int p = blockIdx.x >> 3;
    const int sA = p, sB = 127 - p;
    const int nA = (sA>>2) + 1, nB = (sB>>2) + 1;
    const int NU = nA + nB;                // == 33
    const size_t batchoff = (size_t)b * T_ * 64;

    const bf16x8* qfp = reinterpret_cast<const bf16x8*>(Qfrag);
    const bf16x8* kfp = reinterpret_cast<const bf16x8*>(Kfrag);
    const bf16x8* vfp = reinterpret_cast<const bf16x8*>(Vfrag);
    char* pw = (char*)&Pl[w][0];

    const int qrA = sA*16 + l15, qrB = sB*16 + l15;
    const bf16x8 qA0 = qfp[(size_t)((b*128 + sA)*2 + 0)*64 + l];
    const bf16x8 qA1 = qfp[(size_t)((b*128 + sA)*2 + 1)*64 + l];
    const bf16x8 qB0 = qfp[(size_t)((b*128 + sB)*2 + 0)*64 + l];
    const bf16x8 qB1 = qfp[(size_t)((b*128 + sB)*2 + 1)*64 + l];

    f32x4 oA[4], oB[4];
    #pragma unroll
    for (int i=0;i<4;++i){ oA[i] = (f32x4){0.f,0.f,0.f,0.f}; oB[i] = (f32x4){0.f,0.f,0.f,0.f}; }
    float mA = -1e30f, lA = 0.f, mB = -1e30f, lB = 0.f;   // lA/lB are per-LANE partials

    bf16x8 kf[8], vf[8];

    {
        const int u0 = w;
        const int kvt = (u0 < nA ? u0 : u0 - nA);
        #pragma unroll
        for (int ks=0;ks<2;++ks)
            #pragma unroll
            for (int nt=0;nt<4;++nt)
                kf[ks*4+nt] = kfp[(size_t)(((b*32 + kvt)*4 + nt)*2 + ks)*64 + l];
    }

    auto body = [&](f32x4 (&o)[4], float &mrun, float &lrun,
                    const bf16x8 &qf0, const bf16x8 &qf1,
                    int qrow, int kv0, bool diag, bool hasN, int kvtn)
    {
        f32x4 s4[4];
        #pragma unroll
        for (int nt=0;nt<4;++nt) s4[nt] = (f32x4){0.f,0.f,0.f,0.f};
        __builtin_amdgcn_s_setprio(1);
        #pragma unroll
        for (int ks=0;ks<2;++ks){
            const bf16x8 qf = ks ? qf1 : qf0;
            #pragma unroll
            for (int nt=0;nt<4;++nt)
                s4[nt] = __builtin_amdgcn_mfma_f32_16x16x32_bf16(kf[ks*4+nt], qf, s4[nt], 0,0,0);
        }
        __builtin_amdgcn_s_setprio(0);

        if (hasN){
            #pragma unroll
            for (int ks=0;ks<2;++ks)
                #pragma unroll
                for (int nt=0;nt<4;++nt)
                    kf[ks*4+nt] = kfp[(size_t)(((b*32 + kvtn)*4 + nt)*2 + ks)*64 + l];
        }

        if (diag){
            #pragma unroll
            for (int nt=0;nt<4;++nt)
                #pragma unroll
                for (int rr=0;rr<4;++rr){
                    const int kv = kv0 + nt*16 + lg*4 + rr;
                    if (kv > qrow) s4[nt][rr] = -1e30f;
                }
        }

        // ---- shfl-free softmax fast path ----
        float pmLoc;
        {
            float m0 = fmaxf(fmaxf(s4[0][0],s4[0][1]), fmaxf(s4[0][2],s4[0][3]));
            float m1 = fmaxf(fmaxf(s4[1][0],s4[1][1]), fmaxf(s4[1][2],s4[1][3]));
            float m2 = fmaxf(fmaxf(s4[2][0],s4[2][1]), fmaxf(s4[2][2],s4[2][3]));
            float m3 = fmaxf(fmaxf(s4[3][0],s4[3][1]), fmaxf(s4[3][2],s4[3][3]));
            pmLoc = fmaxf(fmaxf(m0,m1), fmaxf(m2,m3));
        }
        if (__any(pmLoc > mrun + 8.0f)){
            float pm = pmLoc;
            pm = fmaxf(pm, __shfl_xor(pm, 16));
            pm = fmaxf(pm, __shfl_xor(pm, 32));
            const float mn = fmaxf(mrun, pm);
            const float scl = exp2f(mrun - mn);
            mrun = mn; lrun *= scl;
            #pragma unroll
            for (int dt=0;dt<4;++dt)
                #pragma unroll
                for (int j=0;j<4;++j) o[dt][j] *= scl;
        }
        float rs = 0.f;
        #pragma unroll
        for (int nt=0;nt<4;++nt)
            #pragma unroll
            for (int rr=0;rr<4;++rr){
                const float pv = exp2f(s4[nt][rr] - mrun);
                s4[nt][rr] = pv; rs += pv;
            }
        lrun += rs;   // per-lane partial; reduced at merge

        #pragma unroll
        for (int nt=0;nt<4;++nt){
            u16x4 pk;
            #pragma unroll
            for (int rr=0;rr<4;++rr) pk[rr] = (unsigned short)f2bf(s4[nt][rr]);
            *reinterpret_cast<u16x4*>(pw + l15*128 + ((nt*32 + lg*8) ^ ((l15&7)<<4))) = pk;
        }

        __builtin_amdgcn_s_setprio(1);
        #pragma unroll
        for (int ks=0;ks<2;++ks){
            bf16x8 pf = *reinterpret_cast<const bf16x8*>(pw + l15*128 + ((ks*64 + lg*16) ^ ((l15&7)<<4)));
            #pragma unroll
            for (int dt=0;dt<4;++dt)
                o[dt] = __builtin_amdgcn_mfma_f32_16x16x32_bf16(vf[ks*4+dt], pf, o[dt], 0,0,0);
        }
        __builtin_amdgcn_s_setprio(0);
    };

    for (int u = w; u < NU; u += 4){
        const bool isA = (u < nA);
        const int kvt = isA ? u : (u - nA);
        const int kv0 = kvt*64;
        const bool diag = isA ? (kvt == nA-1) : (kvt == nB-1);

        #pragma unroll
        for (int ks=0;ks<2;++ks)
            #pragma unroll
            for (int dt=0;dt<4;++dt)
                vf[ks*4+dt] = vfp[(size_t)(((b*32 + kvt)*4 + dt)*2 + ks)*64 + l];

        const int un = u + 4;
        const bool hasN = un < NU;
        const int kvtn = hasN ? (un < nA ? un : un - nA) : 0;

        if (isA) body(oA, mA, lA, qA0, qA1, qrA, kv0, diag, hasN, kvtn);
        else     body(oB, mB, lB, qB0, qB1, qrB, kv0, diag, hasN, kvtn);
    }

    #pragma unroll
    for (int dt=0;dt<4;++dt){
        *reinterpret_cast<f32x4*>(&Oorg[w][0][l15*64 + dt*16 + lg*4]) = oA[dt];
        *reinterpret_cast<f32x4*>(&Oorg[w][1][l15*64 + dt*16 + lg*4]) = oB[dt];
    }
    Lorg[w][0][l] = lA;
    Lorg[w][1][l] = lB;
    if (lg == 0){
        Morg[w][0][l15] = mA;
        Morg[w][1][l15] = mB;
    }
    __syncthreads();
    {
        const int h = tid>>7, q = (tid>>3)&15, d0 = (tid&7)*8;
        const float m0=Morg[0][h][q], m1=Morg[1][h][q], m2=Morg[2][h][q], m3=Morg[3][h][q];
        const float M = fmaxf(fmaxf(m0,m1), fmaxf(m2,m3));
        const float a0=exp2f(m0-M), a1=exp2f(m1-M), a2=exp2f(m2-M), a3=exp2f(m3-M);
        float L = 0.f;
        #pragma unroll
        for (int gg=0; gg<4; ++gg){
            L += a0*Lorg[0][h][gg*16+q] + a1*Lorg[1][h][gg*16+q]
               + a2*Lorg[2][h][gg*16+q] + a3*Lorg[3][h][gg*16+q];
        }
        const float inv = 1.0f / L;
        const int s = h ? sB : sA;
        float* op = out + batchoff + (size_t)(s*16 + q)*64 + d0;
        #pragma unroll
        for (int j=0;j<8;++j){
            const float v = a0*Oorg[0][h][q*64+d0+j] + a1*Oorg[1][h][q*64+d0+j]
                          + a2*Oorg[2][h][q*64+d0+j] + a3*Oorg[3][h][q*64+d0+j];
            op[j] = v * inv;
        }
    }
}

extern "C" void kernel_launch(void* const* d_in, const int* in_sizes, int n_in,
                              void* d_out, int out_size, void* d_ws, size_t ws_size,
                              hipStream_t stream) {
    const float* x  = (const float*)d_in[0];
    const float* Wq = (const float*)d_in[1];
    const float* Wk = (const float*)d_in[2];
    const float* Wv = (const float*)d_in[3];
    float* out = (float*)d_out;

    const size_t NTOK = (size_t)B_*T_*64;   // 1M elems per tensor
    __hip_bfloat16* Wfrag = (__hip_bfloat16*)d_ws;      // 384 KB
    __hip_bfloat16* Qfrag = Wfrag + (size_t)24576*8;
    __hip_bfloat16* Kfrag = Qfrag + NTOK;
    __hip_bfloat16* Vfrag = Kfrag + NTOK;

    wconv_kernel<<<96, 256, 0, stream>>>(Wq, Wk, Wv, Wfrag);
    proj_kernel<<<512, 384, 0, stream>>>(x, Wfrag, Qfrag, Kfrag, Vfrag);
    fattn_kernel<<<512, 256, 0, stream>>>(Qfrag, Kfrag, Vfrag, out);
}

// Round 11
// 41.273 us; speedup vs baseline: 1.1492x; 1.1492x over previous
//
#include <hip/hip_runtime.h>
#include <hip/hip_bf16.h>
#include <cstdint>
#include <cstddef>

#define B_ 8
#define T_ 2048
#define E_ 1024
#define D_ 64

typedef __attribute__((ext_vector_type(8))) short bf16x8;
typedef __attribute__((ext_vector_type(4))) float f32x4;
typedef __attribute__((ext_vector_type(16))) float f32x16;
typedef __attribute__((ext_vector_type(4))) unsigned short u16x4;

#define QSCALE 0.1803368801111204f  // 0.125 * log2(e)

__device__ __forceinline__ short f2bf(float f){
    __hip_bfloat16 h = __float2bfloat16(f);
    return *reinterpret_cast<short*>(&h);
}

__device__ __forceinline__ bf16x8 cvt8v(const f32x4 a, const f32x4 b){
    bf16x8 r;
    r[0]=f2bf(a[0]); r[1]=f2bf(a[1]); r[2]=f2bf(a[2]); r[3]=f2bf(a[3]);
    r[4]=f2bf(b[0]); r[5]=f2bf(b[1]); r[6]=f2bf(b[2]); r[7]=f2bf(b[3]);
    return r;
}

// ---------- W -> MFMA-fragment-linear layout (unchanged) ----------
__global__ __launch_bounds__(256) void wconv_kernel(
    const float* __restrict__ Wq, const float* __restrict__ Wk,
    const float* __restrict__ Wv, __hip_bfloat16* __restrict__ Wfrag)
{
    const int g = blockIdx.x*256 + threadIdx.x;   // [0, 24576)
    const int l = g & 63;
    const int ntg = (g >> 6) % 6;
    const int cg = g / 384;
    const int n = ntg*32 + (l & 31);
    const int m = n >> 6;
    const int ncol = n & 63;
    const float* W = (m==0) ? Wq : (m==1) ? Wk : Wv;
    const float sc = (m==0) ? QSCALE : 1.0f;
    const int k0 = cg*16 + (l>>5)*8;
    bf16x8 r;
    #pragma unroll
    for (int j=0;j<8;++j)
        r[j] = f2bf(W[(size_t)(k0+j)*64 + ncol] * sc);
    *reinterpret_cast<bf16x8*>(Wfrag + (size_t)g*8) = r;
}

// ---------- QKV projection v6: R9-v4 main loop + single-barrier direct-frag epilogue ----------
__global__ __launch_bounds__(384, 3) void proj_kernel(
    const float* __restrict__ x, const __hip_bfloat16* __restrict__ Wfrag,
    __hip_bfloat16* __restrict__ Qfrag, __hip_bfloat16* __restrict__ Kfrag,
    __hip_bfloat16* __restrict__ Vfrag)
{
    __shared__ __align__(16) unsigned short xs[2][32*64];   // 8 KB dbuf, bf16, XOR-swizzled
    __shared__ float vtQ[32*65];                            // 3 x 8.3 KB transpose buffers
    __shared__ float vtK[32*65];
    __shared__ float vtV[32*65];
    const int tid = threadIdx.x;
    const int w = tid>>6, l = tid&63;
    const int l31 = l&31, kg = l>>5;
    const float* xp = x + (size_t)blockIdx.x*32*E_;

    f32x16 acc;
    #pragma unroll
    for (int j=0;j<16;++j) acc[j]=0.f;

    const bf16x8* Wfp = reinterpret_cast<const bf16x8*>(Wfrag);

    bf16x8 btA[4], btB[4];
    #pragma unroll
    for (int c=0;c<4;++c)
        btA[c] = Wfp[(size_t)(((0*4+c)*6 + w)*64 + l)];

    const int srow = tid>>3, sc8 = tid&7;

    if (tid < 256){
        f32x4 v0 = *reinterpret_cast<const f32x4*>(xp + (size_t)srow*E_ + sc8*8);
        f32x4 v1 = *reinterpret_cast<const f32x4*>(xp + (size_t)srow*E_ + sc8*8 + 4);
        *reinterpret_cast<bf16x8*>((char*)&xs[0][0] + srow*128 + ((sc8*16) ^ ((srow&7)<<4))) = cvt8v(v0, v1);
    }
    __syncthreads();

#define PSTEP(T, BC, BN)                                                       \
    {                                                                          \
        const int t = (T);                                                     \
        if (t+1 < 16){                                                         \
            _Pragma("unroll")                                                  \
            for (int c=0;c<4;++c)                                              \
                BN[c] = Wfp[(size_t)((((t+1)*4+c)*6 + w)*64 + l)];             \
        }                                                                      \
        f32x4 xa0, xa1;                                                        \
        if (t+1 < 16 && tid < 256){                                            \
            xa0 = *reinterpret_cast<const f32x4*>(xp + (size_t)srow*E_ + (t+1)*64 + sc8*8);     \
            xa1 = *reinterpret_cast<const f32x4*>(xp + (size_t)srow*E_ + (t+1)*64 + sc8*8 + 4); \
        }                                                                      \
        const char* xb = (const char*)&xs[t&1][0];                             \
        _Pragma("unroll")                                                      \
        for (int c=0;c<4;++c){                                                 \
            bf16x8 af = *reinterpret_cast<const bf16x8*>(xb + l31*128 + (((c*32 + kg*16)) ^ ((l31&7)<<4))); \
            acc = __builtin_amdgcn_mfma_f32_32x32x16_bf16(af, BC[c], acc, 0,0,0); \
        }                                                                      \
        if (t+1 < 16){                                                         \
            if (tid < 256)                                                     \
                *reinterpret_cast<bf16x8*>((char*)&xs[(t+1)&1][0] + srow*128 + ((sc8*16) ^ ((srow&7)<<4))) = cvt8v(xa0, xa1); \
            __syncthreads();                                                   \
        }                                                                      \
    }

    for (int t2=0; t2<8; ++t2){
        PSTEP(2*t2,   btA, btB)
        PSTEP(2*t2+1, btB, btA)
    }
#undef PSTEP

    // ---- epilogue: all 3 transposes into parallel vt buffers, ONE barrier, frag stores ----
    {
        float* vtX = (w<2) ? vtQ : (w<4) ? vtK : vtV;
        const int col = (w&1)*32 + l31;
        #pragma unroll
        for (int reg=0; reg<16; ++reg){
            const int mr = (reg&3) + 8*(reg>>2) + 4*kg;
            vtX[mr*65 + col] = acc[reg];
        }
    }
    __syncthreads();
    if (tid < 256){
        const int q = blockIdx.x, b = q>>6, q63 = q&63, t = q63>>1;
        const int su  = (tid>>7)&1, ksw = (tid>>6)&1, lw = tid&63;
        const int lw15 = lw&15, lwg = lw>>4;
        // Q frag
        {
            f32x4 a0, a1;
            #pragma unroll
            for (int j=0;j<4;++j) a0[j] = vtQ[(su*16+lw15)*65 + ksw*32 + lwg*8 + j];
            #pragma unroll
            for (int j=0;j<4;++j) a1[j] = vtQ[(su*16+lw15)*65 + ksw*32 + lwg*8 + 4 + j];
            const size_t gi = ((size_t)(b*128 + 2*q63 + su)*2 + ksw)*64 + lw;
            *reinterpret_cast<bf16x8*>(Qfrag + gi*8) = cvt8v(a0, a1);
        }
        // K frag
        {
            f32x4 a0, a1;
            #pragma unroll
            for (int j=0;j<4;++j) a0[j] = vtK[(su*16+lw15)*65 + ksw*32 + lwg*8 + j];
            #pragma unroll
            for (int j=0;j<4;++j) a1[j] = vtK[(su*16+lw15)*65 + ksw*32 + lwg*8 + 4 + j];
            const int nt = (q&1)*2 + su;
            const size_t gi = (((size_t)(b*32 + t)*4 + nt)*2 + ksw)*64 + lw;
            *reinterpret_cast<bf16x8*>(Kfrag + gi*8) = cvt8v(a0, a1);
        }
        // V frag (transposed)
        {
            const int dt = tid>>6;   // 0..3
            bf16x8 pk;
            #pragma unroll
            for (int j=0;j<8;++j)
                pk[j] = f2bf(vtV[(lwg*8+j)*65 + dt*16 + lw15]);
            const size_t gi = (((size_t)(b*32 + t)*4 + dt)*2 + (q&1))*64 + lw;
            *reinterpret_cast<bf16x8*>(Vfrag + gi*8) = pk;
        }
    }
}

// ---------- flash attention v5 (byte-identical to R9) ----------
__global__ __launch_bounds__(256, 2) void fattn_kernel(
    const __hip_bfloat16* __restrict__ Qfrag, const __hip_bfloat16* __restrict__ Kfrag,
    const __hip_bfloat16* __restrict__ Vfrag, float* __restrict__ out)
{
    __shared__ __align__(16) unsigned short Pl[4][16*64];
    __shared__ float Morg[4][2][16];
    __shared__ float Lorg[4][2][16];
    __shared__ __align__(16) float Oorg[4][2][16*64];

    const int tid = threadIdx.x;
    const int w = tid>>6, l = tid&63;
    const int l15 = l&15, lg = l>>4;

    const int b = blockIdx.x & 7;
    const int p = blockIdx.x >> 3;
    const int sA = p, sB = 127 - p;
    const int nA = (sA>>2) + 1, nB = (sB>>2) + 1;
    const int NU = nA + nB;                // == 33
    const size_t batchoff = (size_t)b * T_ * 64;

    const bf16x8* qfp = reinterpret_cast<const bf16x8*>(Qfrag);
    const bf16x8* kfp = reinterpret_cast<const bf16x8*>(Kfrag);
    const bf16x8* vfp = reinterpret_cast<const bf16x8*>(Vfrag);
    char* pw = (char*)&Pl[w][0];

    const int qrA = sA*16 + l15, qrB = sB*16 + l15;
    const bf16x8 qA0 = qfp[(size_t)((b*128 + sA)*2 + 0)*64 + l];
    const bf16x8 qA1 = qfp[(size_t)((b*128 + sA)*2 + 1)*64 + l];
    const bf16x8 qB0 = qfp[(size_t)((b*128 + sB)*2 + 0)*64 + l];
    const bf16x8 qB1 = qfp[(size_t)((b*128 + sB)*2 + 1)*64 + l];

    f32x4 oA[4], oB[4];
    #pragma unroll
    for (int i=0;i<4;++i){ oA[i] = (f32x4){0.f,0.f,0.f,0.f}; oB[i] = (f32x4){0.f,0.f,0.f,0.f}; }
    float mA = -1e30f, lA = 0.f, mB = -1e30f, lB = 0.f;

    bf16x8 kf[8], vf[8];

    {
        const int u0 = w;
        const int kvt = (u0 < nA ? u0 : u0 - nA);
        #pragma unroll
        for (int ks=0;ks<2;++ks)
            #pragma unroll
            for (int nt=0;nt<4;++nt)
                kf[ks*4+nt] = kfp[(size_t)(((b*32 + kvt)*4 + nt)*2 + ks)*64 + l];
    }

    auto body = [&](f32x4 (&o)[4], float &mrun, float &lrun,
                    const bf16x8 &qf0, const bf16x8 &qf1,
                    int qrow, int kv0, bool diag, bool hasN, int kvtn)
    {
        f32x4 s4[4];
        #pragma unroll
        for (int nt=0;nt<4;++nt) s4[nt] = (f32x4){0.f,0.f,0.f,0.f};
        __builtin_amdgcn_s_setprio(1);
        #pragma unroll
        for (int ks=0;ks<2;++ks){
            const bf16x8 qf = ks ? qf1 : qf0;
            #pragma unroll
            for (int nt=0;nt<4;++nt)
                s4[nt] = __builtin_amdgcn_mfma_f32_16x16x32_bf16(kf[ks*4+nt], qf, s4[nt], 0,0,0);
        }
        __builtin_amdgcn_s_setprio(0);

        if (hasN){
            #pragma unroll
            for (int ks=0;ks<2;++ks)
                #pragma unroll
                for (int nt=0;nt<4;++nt)
                    kf[ks*4+nt] = kfp[(size_t)(((b*32 + kvtn)*4 + nt)*2 + ks)*64 + l];
        }

        if (diag){
            #pragma unroll
            for (int nt=0;nt<4;++nt)
                #pragma unroll
                for (int rr=0;rr<4;++rr){
                    const int kv = kv0 + nt*16 + lg*4 + rr;
                    if (kv > qrow) s4[nt][rr] = -1e30f;
                }
        }

        float pm;
        {
            float m0 = fmaxf(fmaxf(s4[0][0],s4[0][1]), fmaxf(s4[0][2],s4[0][3]));
            float m1 = fmaxf(fmaxf(s4[1][0],s4[1][1]), fmaxf(s4[1][2],s4[1][3]));
            float m2 = fmaxf(fmaxf(s4[2][0],s4[2][1]), fmaxf(s4[2][2],s4[2][3]));
            float m3 = fmaxf(fmaxf(s4[3][0],s4[3][1]), fmaxf(s4[3][2],s4[3][3]));
            pm = fmaxf(fmaxf(m0,m1), fmaxf(m2,m3));
        }
        pm = fmaxf(pm, __shfl_xor(pm, 16));
        pm = fmaxf(pm, __shfl_xor(pm, 32));
        if (pm > mrun + 8.0f){
            const float scl = exp2f(mrun - pm);
            mrun = pm; lrun *= scl;
            #pragma unroll
            for (int dt=0;dt<4;++dt)
                #pragma unroll
                for (int j=0;j<4;++j) o[dt][j] *= scl;
        }
        float rs = 0.f;
        #pragma unroll
        for (int nt=0;nt<4;++nt)
            #pragma unroll
            for (int rr=0;rr<4;++rr){
                const float pv = exp2f(s4[nt][rr] - mrun);
                s4[nt][rr] = pv; rs += pv;
            }
        rs += __shfl_xor(rs, 16);
        rs += __shfl_xor(rs, 32);
        lrun += rs;

        #pragma unroll
        for (int nt=0;nt<4;++nt){
            u16x4 pk;
            #pragma unroll
            for (int rr=0;rr<4;++rr) pk[rr] = (unsigned short)f2bf(s4[nt][rr]);
            *reinterpret_cast<u16x4*>(pw + l15*128 + ((nt*32 + lg*8) ^ ((l15&7)<<4))) = pk;
        }

        __builtin_amdgcn_s_setprio(1);
        #pragma unroll
        for (int ks=0;ks<2;++ks){
            bf16x8 pf = *reinterpret_cast<const bf16x8*>(pw + l15*128 + ((ks*64 + lg*16) ^ ((l15&7)<<4)));
            #pragma unroll
            for (int dt=0;dt<4;++dt)
                o[dt] = __builtin_amdgcn_mfma_f32_16x16x32_bf16(vf[ks*4+dt], pf, o[dt], 0,0,0);
        }
        __builtin_amdgcn_s_setprio(0);
    };

    for (int u = w; u < NU; u += 4){
        const bool isA = (u < nA);
        const int kvt = isA ? u : (u - nA);
        const int kv0 = kvt*64;
        const bool diag = isA ? (kvt == nA-1) : (kvt == nB-1);

        #pragma unroll
        for (int ks=0;ks<2;++ks)
            #pragma unroll
            for (int dt=0;dt<4;++dt)
                vf[ks*4+dt] = vfp[(size_t)(((b*32 + kvt)*4 + dt)*2 + ks)*64 + l];

        const int un = u + 4;
        const bool hasN = un < NU;
        const int kvtn = hasN ? (un < nA ? un : un - nA) : 0;

        if (isA) body(oA, mA, lA, qA0, qA1, qrA, kv0, diag, hasN, kvtn);
        else     body(oB, mB, lB, qB0, qB1, qrB, kv0, diag, hasN, kvtn);
    }

    #pragma unroll
    for (int dt=0;dt<4;++dt){
        *reinterpret_cast<f32x4*>(&Oorg[w][0][l15*64 + dt*16 + lg*4]) = oA[dt];
        *reinterpret_cast<f32x4*>(&Oorg[w][1][l15*64 + dt*16 + lg*4]) = oB[dt];
    }
    if (lg == 0){
        Morg[w][0][l15] = mA; Lorg[w][0][l15] = lA;
        Morg[w][1][l15] = mB; Lorg[w][1][l15] = lB;
    }
    __syncthreads();
    {
        const int h = tid>>7, q = (tid>>3)&15, d0 = (tid&7)*8;
        const float m0=Morg[0][h][q], m1=Morg[1][h][q], m2=Morg[2][h][q], m3=Morg[3][h][q];
        const float M = fmaxf(fmaxf(m0,m1), fmaxf(m2,m3));
        const float a0=exp2f(m0-M), a1=exp2f(m1-M), a2=exp2f(m2-M), a3=exp2f(m3-M);
        const float L = a0*Lorg[0][h][q] + a1*Lorg[1][h][q] + a2*Lorg[2][h][q] + a3*Lorg[3][h][q];
        const float inv = 1.0f / L;
        const int s = h ? sB : sA;
        float* op = out + batchoff + (size_t)(s*16 + q)*64 + d0;
        #pragma unroll
        for (int j=0;j<8;++j){
            const float v = a0*Oorg[0][h][q*64+d0+j] + a1*Oorg[1][h][q*64+d0+j]
                          + a2*Oorg[2][h][q*64+d0+j] + a3*Oorg[3][h][q*64+d0+j];
            op[j] = v * inv;
        }
    }
}

extern "C" void kernel_launch(void* const* d_in, const int* in_sizes, int n_in,
                              void* d_out, int out_size, void* d_ws, size_t ws_size,
                              hipStream_t stream) {
    const float* x  = (const float*)d_in[0];
    const float* Wq = (const float*)d_in[1];
    const float* Wk = (const float*)d_in[2];
    const float* Wv = (const float*)d_in[3];
    float* out = (float*)d_out;

    const size_t NTOK = (size_t)B_*T_*64;   // 1M elems per tensor
    __hip_bfloat16* Wfrag = (__hip_bfloat16*)d_ws;      // 384 KB
    __hip_bfloat16* Qfrag = Wfrag + (size_t)24576*8;
    __hip_bfloat16* Kfrag = Qfrag + NTOK;
    __hip_bfloat16* Vfrag = Kfrag + NTOK;

    wconv_kernel<<<96, 256, 0, stream>>>(Wq, Wk, Wv, Wfrag);
    proj_kernel<<<512, 384, 0, stream>>>(x, Wfrag, Qfrag, Kfrag, Vfrag);
    fattn_kernel<<<512, 256, 0, stream>>>(Qfrag, Kfrag, Vfrag, out);
}

// Round 12
// 39.814 us; speedup vs baseline: 1.1914x; 1.0366x over previous
//
#include <hip/hip_runtime.h>
#include <hip/hip_bf16.h>
#include <cstdint>
#include <cstddef>

#define B_ 8
#define T_ 2048
#define E_ 1024
#define D_ 64

typedef __attribute__((ext_vector_type(8))) short bf16x8;
typedef __attribute__((ext_vector_type(4))) float f32x4;
typedef __attribute__((ext_vector_type(16))) float f32x16;
typedef __attribute__((ext_vector_type(4))) unsigned short u16x4;

#define QSCALE 0.1803368801111204f  // 0.125 * log2(e)

__device__ __forceinline__ short f2bf(float f){
    __hip_bfloat16 h = __float2bfloat16(f);
    return *reinterpret_cast<short*>(&h);
}

__device__ __forceinline__ bf16x8 cvt8v(const f32x4 a, const f32x4 b){
    bf16x8 r;
    r[0]=f2bf(a[0]); r[1]=f2bf(a[1]); r[2]=f2bf(a[2]); r[3]=f2bf(a[3]);
    r[4]=f2bf(b[0]); r[5]=f2bf(b[1]); r[6]=f2bf(b[2]); r[7]=f2bf(b[3]);
    return r;
}

// ---------- W -> MFMA-fragment-linear layout (unchanged) ----------
__global__ __launch_bounds__(256) void wconv_kernel(
    const float* __restrict__ Wq, const float* __restrict__ Wk,
    const float* __restrict__ Wv, __hip_bfloat16* __restrict__ Wfrag)
{
    const int g = blockIdx.x*256 + threadIdx.x;   // [0, 24576)
    const int l = g & 63;
    const int ntg = (g >> 6) % 6;
    const int cg = g / 384;
    const int n = ntg*32 + (l & 31);
    const int m = n >> 6;
    const int ncol = n & 63;
    const float* W = (m==0) ? Wq : (m==1) ? Wk : Wv;
    const float sc = (m==0) ? QSCALE : 1.0f;
    const int k0 = cg*16 + (l>>5)*8;
    bf16x8 r;
    #pragma unroll
    for (int j=0;j<8;++j)
        r[j] = f2bf(W[(size_t)(k0+j)*64 + ncol] * sc);
    *reinterpret_cast<bf16x8*>(Wfrag + (size_t)g*8) = r;
}

// ---------- QKV projection v6 (UNCHANGED from R11) ----------
__global__ __launch_bounds__(384, 3) void proj_kernel(
    const float* __restrict__ x, const __hip_bfloat16* __restrict__ Wfrag,
    __hip_bfloat16* __restrict__ Qfrag, __hip_bfloat16* __restrict__ Kfrag,
    __hip_bfloat16* __restrict__ Vfrag)
{
    __shared__ __align__(16) unsigned short xs[2][32*64];
    __shared__ float vtQ[32*65];
    __shared__ float vtK[32*65];
    __shared__ float vtV[32*65];
    const int tid = threadIdx.x;
    const int w = tid>>6, l = tid&63;
    const int l31 = l&31, kg = l>>5;
    const float* xp = x + (size_t)blockIdx.x*32*E_;

    f32x16 acc;
    #pragma unroll
    for (int j=0;j<16;++j) acc[j]=0.f;

    const bf16x8* Wfp = reinterpret_cast<const bf16x8*>(Wfrag);

    bf16x8 btA[4], btB[4];
    #pragma unroll
    for (int c=0;c<4;++c)
        btA[c] = Wfp[(size_t)(((0*4+c)*6 + w)*64 + l)];

    const int srow = tid>>3, sc8 = tid&7;

    if (tid < 256){
        f32x4 v0 = *reinterpret_cast<const f32x4*>(xp + (size_t)srow*E_ + sc8*8);
        f32x4 v1 = *reinterpret_cast<const f32x4*>(xp + (size_t)srow*E_ + sc8*8 + 4);
        *reinterpret_cast<bf16x8*>((char*)&xs[0][0] + srow*128 + ((sc8*16) ^ ((srow&7)<<4))) = cvt8v(v0, v1);
    }
    __syncthreads();

#define PSTEP(T, BC, BN)                                                       \
    {                                                                          \
        const int t = (T);                                                     \
        if (t+1 < 16){                                                         \
            _Pragma("unroll")                                                  \
            for (int c=0;c<4;++c)                                              \
                BN[c] = Wfp[(size_t)((((t+1)*4+c)*6 + w)*64 + l)];             \
        }                                                                      \
        f32x4 xa0, xa1;                                                        \
        if (t+1 < 16 && tid < 256){                                            \
            xa0 = *reinterpret_cast<const f32x4*>(xp + (size_t)srow*E_ + (t+1)*64 + sc8*8);     \
            xa1 = *reinterpret_cast<const f32x4*>(xp + (size_t)srow*E_ + (t+1)*64 + sc8*8 + 4); \
        }                                                                      \
        const char* xb = (const char*)&xs[t&1][0];                             \
        _Pragma("unroll")                                                      \
        for (int c=0;c<4;++c){                                                 \
            bf16x8 af = *reinterpret_cast<const bf16x8*>(xb + l31*128 + (((c*32 + kg*16)) ^ ((l31&7)<<4))); \
            acc = __builtin_amdgcn_mfma_f32_32x32x16_bf16(af, BC[c], acc, 0,0,0); \
        }                                                                      \
        if (t+1 < 16){                                                         \
            if (tid < 256)                                                     \
                *reinterpret_cast<bf16x8*>((char*)&xs[(t+1)&1][0] + srow*128 + ((sc8*16) ^ ((srow&7)<<4))) = cvt8v(xa0, xa1); \
            __syncthreads();                                                   \
        }                                                                      \
    }

    for (int t2=0; t2<8; ++t2){
        PSTEP(2*t2,   btA, btB)
        PSTEP(2*t2+1, btB, btA)
    }
#undef PSTEP

    {
        float* vtX = (w<2) ? vtQ : (w<4) ? vtK : vtV;
        const int col = (w&1)*32 + l31;
        #pragma unroll
        for (int reg=0; reg<16; ++reg){
            const int mr = (reg&3) + 8*(reg>>2) + 4*kg;
            vtX[mr*65 + col] = acc[reg];
        }
    }
    __syncthreads();
    if (tid < 256){
        const int q = blockIdx.x, b = q>>6, q63 = q&63, t = q63>>1;
        const int su  = (tid>>7)&1, ksw = (tid>>6)&1, lw = tid&63;
        const int lw15 = lw&15, lwg = lw>>4;
        {
            f32x4 a0, a1;
            #pragma unroll
            for (int j=0;j<4;++j) a0[j] = vtQ[(su*16+lw15)*65 + ksw*32 + lwg*8 + j];
            #pragma unroll
            for (int j=0;j<4;++j) a1[j] = vtQ[(su*16+lw15)*65 + ksw*32 + lwg*8 + 4 + j];
            const size_t gi = ((size_t)(b*128 + 2*q63 + su)*2 + ksw)*64 + lw;
            *reinterpret_cast<bf16x8*>(Qfrag + gi*8) = cvt8v(a0, a1);
        }
        {
            f32x4 a0, a1;
            #pragma unroll
            for (int j=0;j<4;++j) a0[j] = vtK[(su*16+lw15)*65 + ksw*32 + lwg*8 + j];
            #pragma unroll
            for (int j=0;j<4;++j) a1[j] = vtK[(su*16+lw15)*65 + ksw*32 + lwg*8 + 4 + j];
            const int nt = (q&1)*2 + su;
            const size_t gi = (((size_t)(b*32 + t)*4 + nt)*2 + ksw)*64 + lw;
            *reinterpret_cast<bf16x8*>(Kfrag + gi*8) = cvt8v(a0, a1);
        }
        {
            const int dt = tid>>6;
            bf16x8 pk;
            #pragma unroll
            for (int j=0;j<8;++j)
                pk[j] = f2bf(vtV[(lwg*8+j)*65 + dt*16 + lw15]);
            const size_t gi = (((size_t)(b*32 + t)*4 + dt)*2 + (q&1))*64 + lw;
            *reinterpret_cast<bf16x8*>(Vfrag + gi*8) = pk;
        }
    }
}

// ---------- flash attention v7: dual-unit bodies (ILP-2), merged softmax, deferred l ----------
__global__ __launch_bounds__(256, 2) void fattn_kernel(
    const __hip_bfloat16* __restrict__ Qfrag, const __hip_bfloat16* __restrict__ Kfrag,
    const __hip_bfloat16* __restrict__ Vfrag, float* __restrict__ out)
{
    __shared__ __align__(16) unsigned short Pl[4][2048];   // 16 KB: 2 P tiles per wave
    __shared__ float Morg[4][2][16];
    __shared__ float Lorg[4][2][64];                       // per-lane l partials
    __shared__ __align__(16) float Oorg[4][2][16*64];      // 32 KB

    const int tid = threadIdx.x;
    const int w = tid>>6, l = tid&63;
    const int l15 = l&15, lg = l>>4;

    const int b = blockIdx.x & 7;
    const int p = blockIdx.x >> 3;
    const int sA = p, sB = 127 - p;
    const int nA = (sA>>2) + 1, nB = (sB>>2) + 1;   // nA + nB == 33
    const size_t batchoff = (size_t)b * T_ * 64;

    const bf16x8* qfp = reinterpret_cast<const bf16x8*>(Qfrag);
    const bf16x8* kfp = reinterpret_cast<const bf16x8*>(Kfrag);
    const bf16x8* vfp = reinterpret_cast<const bf16x8*>(Vfrag);
    char* pw = (char*)&Pl[w][0];

    const int qrA = sA*16 + l15, qrB = sB*16 + l15;
    const bf16x8 qA0 = qfp[(size_t)((b*128 + sA)*2 + 0)*64 + l];
    const bf16x8 qA1 = qfp[(size_t)((b*128 + sA)*2 + 1)*64 + l];
    const bf16x8 qB0 = qfp[(size_t)((b*128 + sB)*2 + 0)*64 + l];
    const bf16x8 qB1 = qfp[(size_t)((b*128 + sB)*2 + 1)*64 + l];

    f32x4 oA[4], oB[4];
    #pragma unroll
    for (int i=0;i<4;++i){ oA[i] = (f32x4){0.f,0.f,0.f,0.f}; oB[i] = (f32x4){0.f,0.f,0.f,0.f}; }
    float mA = -1e30f, lA = 0.f, mB = -1e30f, lB = 0.f;   // l* are per-LANE partials

    // ---------- single-unit body ----------
    auto single = [&](f32x4 (&o)[4], float &mrun, float &lrun,
                      const bf16x8 &qf0, const bf16x8 &qf1,
                      int qrow, int kvt, int n)
    {
        bf16x8 kf[8], vf[8];
        #pragma unroll
        for (int ks=0;ks<2;++ks)
            #pragma unroll
            for (int nt=0;nt<4;++nt){
                kf[ks*4+nt] = kfp[(size_t)(((b*32 + kvt)*4 + nt)*2 + ks)*64 + l];
                vf[ks*4+nt] = vfp[(size_t)(((b*32 + kvt)*4 + nt)*2 + ks)*64 + l];
            }
        f32x4 s4[4];
        #pragma unroll
        for (int nt=0;nt<4;++nt) s4[nt] = (f32x4){0.f,0.f,0.f,0.f};
        __builtin_amdgcn_s_setprio(1);
        #pragma unroll
        for (int ks=0;ks<2;++ks){
            const bf16x8 qf = ks ? qf1 : qf0;
            #pragma unroll
            for (int nt=0;nt<4;++nt)
                s4[nt] = __builtin_amdgcn_mfma_f32_16x16x32_bf16(kf[ks*4+nt], qf, s4[nt], 0,0,0);
        }
        __builtin_amdgcn_s_setprio(0);

        if (kvt == n-1){
            const int kv0 = kvt*64;
            #pragma unroll
            for (int nt=0;nt<4;++nt)
                #pragma unroll
                for (int rr=0;rr<4;++rr){
                    const int kv = kv0 + nt*16 + lg*4 + rr;
                    if (kv > qrow) s4[nt][rr] = -1e30f;
                }
        }

        float pmLoc;
        {
            float m0 = fmaxf(fmaxf(s4[0][0],s4[0][1]), fmaxf(s4[0][2],s4[0][3]));
            float m1 = fmaxf(fmaxf(s4[1][0],s4[1][1]), fmaxf(s4[1][2],s4[1][3]));
            float m2 = fmaxf(fmaxf(s4[2][0],s4[2][1]), fmaxf(s4[2][2],s4[2][3]));
            float m3 = fmaxf(fmaxf(s4[3][0],s4[3][1]), fmaxf(s4[3][2],s4[3][3]));
            pmLoc = fmaxf(fmaxf(m0,m1), fmaxf(m2,m3));
        }
        if (__any(pmLoc > mrun + 8.0f)){
            float pm = pmLoc;
            pm = fmaxf(pm, __shfl_xor(pm, 16));
            pm = fmaxf(pm, __shfl_xor(pm, 32));
            const float mn = fmaxf(mrun, pm);
            const float scl = exp2f(mrun - mn);
            mrun = mn; lrun *= scl;
            #pragma unroll
            for (int dt=0;dt<4;++dt)
                #pragma unroll
                for (int j=0;j<4;++j) o[dt][j] *= scl;
        }
        float rs = 0.f;
        #pragma unroll
        for (int nt=0;nt<4;++nt)
            #pragma unroll
            for (int rr=0;rr<4;++rr){
                const float pv = exp2f(s4[nt][rr] - mrun);
                s4[nt][rr] = pv; rs += pv;
            }
        lrun += rs;

        #pragma unroll
        for (int nt=0;nt<4;++nt){
            u16x4 pk;
            #pragma unroll
            for (int rr=0;rr<4;++rr) pk[rr] = (unsigned short)f2bf(s4[nt][rr]);
            *reinterpret_cast<u16x4*>(pw + l15*128 + ((nt*32 + lg*8) ^ ((l15&7)<<4))) = pk;
        }
        __builtin_amdgcn_s_setprio(1);
        #pragma unroll
        for (int ks=0;ks<2;++ks){
            bf16x8 pf = *reinterpret_cast<const bf16x8*>(pw + l15*128 + ((ks*64 + lg*16) ^ ((l15&7)<<4)));
            #pragma unroll
            for (int dt=0;dt<4;++dt)
                o[dt] = __builtin_amdgcn_mfma_f32_16x16x32_bf16(vf[ks*4+dt], pf, o[dt], 0,0,0);
        }
        __builtin_amdgcn_s_setprio(0);
    };

    // ---------- dual-unit body (same stripe, shared state; kvt1 < kvt2) ----------
    auto dual = [&](f32x4 (&o)[4], float &mrun, float &lrun,
                    const bf16x8 &qf0, const bf16x8 &qf1,
                    int qrow, int kvt1, int kvt2, int n)
    {
        bf16x8 kf1[8], kf2[8], vf1[8], vf2[8];
        #pragma unroll
        for (int ks=0;ks<2;++ks)
            #pragma unroll
            for (int nt=0;nt<4;++nt){
                kf1[ks*4+nt] = kfp[(size_t)(((b*32 + kvt1)*4 + nt)*2 + ks)*64 + l];
                kf2[ks*4+nt] = kfp[(size_t)(((b*32 + kvt2)*4 + nt)*2 + ks)*64 + l];
            }
        #pragma unroll
        for (int ks=0;ks<2;++ks)
            #pragma unroll
            for (int nt=0;nt<4;++nt){
                vf1[ks*4+nt] = vfp[(size_t)(((b*32 + kvt1)*4 + nt)*2 + ks)*64 + l];
                vf2[ks*4+nt] = vfp[(size_t)(((b*32 + kvt2)*4 + nt)*2 + ks)*64 + l];
            }

        f32x4 s41[4], s42[4];
        #pragma unroll
        for (int nt=0;nt<4;++nt){ s41[nt] = (f32x4){0.f,0.f,0.f,0.f}; s42[nt] = (f32x4){0.f,0.f,0.f,0.f}; }
        __builtin_amdgcn_s_setprio(1);
        #pragma unroll
        for (int ks=0;ks<2;++ks){
            const bf16x8 qf = ks ? qf1 : qf0;
            #pragma unroll
            for (int nt=0;nt<4;++nt)
                s41[nt] = __builtin_amdgcn_mfma_f32_16x16x32_bf16(kf1[ks*4+nt], qf, s41[nt], 0,0,0);
            #pragma unroll
            for (int nt=0;nt<4;++nt)
                s42[nt] = __builtin_amdgcn_mfma_f32_16x16x32_bf16(kf2[ks*4+nt], qf, s42[nt], 0,0,0);
        }
        __builtin_amdgcn_s_setprio(0);

        if (kvt2 == n-1){
            const int kv0 = kvt2*64;
            #pragma unroll
            for (int nt=0;nt<4;++nt)
                #pragma unroll
                for (int rr=0;rr<4;++rr){
                    const int kv = kv0 + nt*16 + lg*4 + rr;
                    if (kv > qrow) s42[nt][rr] = -1e30f;
                }
        }

        float pmLoc;
        {
            float a0 = fmaxf(fmaxf(s41[0][0],s41[0][1]), fmaxf(s41[0][2],s41[0][3]));
            float a1 = fmaxf(fmaxf(s41[1][0],s41[1][1]), fmaxf(s41[1][2],s41[1][3]));
            float a2 = fmaxf(fmaxf(s41[2][0],s41[2][1]), fmaxf(s41[2][2],s41[2][3]));
            float a3 = fmaxf(fmaxf(s41[3][0],s41[3][1]), fmaxf(s41[3][2],s41[3][3]));
            float b0 = fmaxf(fmaxf(s42[0][0],s42[0][1]), fmaxf(s42[0][2],s42[0][3]));
            float b1 = fmaxf(fmaxf(s42[1][0],s42[1][1]), fmaxf(s42[1][2],s42[1][3]));
            float b2 = fmaxf(fmaxf(s42[2][0],s42[2][1]), fmaxf(s42[2][2],s42[2][3]));
            float b3 = fmaxf(fmaxf(s42[3][0],s42[3][1]), fmaxf(s42[3][2],s42[3][3]));
            pmLoc = fmaxf(fmaxf(fmaxf(a0,a1), fmaxf(a2,a3)),
                          fmaxf(fmaxf(b0,b1), fmaxf(b2,b3)));
        }
        if (__any(pmLoc > mrun + 8.0f)){
            float pm = pmLoc;
            pm = fmaxf(pm, __shfl_xor(pm, 16));
            pm = fmaxf(pm, __shfl_xor(pm, 32));
            const float mn = fmaxf(mrun, pm);
            const float scl = exp2f(mrun - mn);
            mrun = mn; lrun *= scl;
            #pragma unroll
            for (int dt=0;dt<4;++dt)
                #pragma unroll
                for (int j=0;j<4;++j) o[dt][j] *= scl;
        }
        float rs = 0.f;
        #pragma unroll
        for (int nt=0;nt<4;++nt)
            #pragma unroll
            for (int rr=0;rr<4;++rr){
                const float pv1 = exp2f(s41[nt][rr] - mrun);
                const float pv2 = exp2f(s42[nt][rr] - mrun);
                s41[nt][rr] = pv1; s42[nt][rr] = pv2;
                rs += pv1 + pv2;
            }
        lrun += rs;

        #pragma unroll
        for (int nt=0;nt<4;++nt){
            u16x4 pk1, pk2;
            #pragma unroll
            for (int rr=0;rr<4;++rr){
                pk1[rr] = (unsigned short)f2bf(s41[nt][rr]);
                pk2[rr] = (unsigned short)f2bf(s42[nt][rr]);
            }
            *reinterpret_cast<u16x4*>(pw + l15*128 + ((nt*32 + lg*8) ^ ((l15&7)<<4))) = pk1;
            *reinterpret_cast<u16x4*>(pw + 2048 + l15*128 + ((nt*32 + lg*8) ^ ((l15&7)<<4))) = pk2;
        }
        __builtin_amdgcn_s_setprio(1);
        #pragma unroll
        for (int ks=0;ks<2;++ks){
            bf16x8 pf1 = *reinterpret_cast<const bf16x8*>(pw + l15*128 + ((ks*64 + lg*16) ^ ((l15&7)<<4)));
            bf16x8 pf2 = *reinterpret_cast<const bf16x8*>(pw + 2048 + l15*128 + ((ks*64 + lg*16) ^ ((l15&7)<<4)));
            #pragma unroll
            for (int dt=0;dt<4;++dt)
                o[dt] = __builtin_amdgcn_mfma_f32_16x16x32_bf16(vf1[ks*4+dt], pf1, o[dt], 0,0,0);
            #pragma unroll
            for (int dt=0;dt<4;++dt)
                o[dt] = __builtin_amdgcn_mfma_f32_16x16x32_bf16(vf2[ks*4+dt], pf2, o[dt], 0,0,0);
        }
        __builtin_amdgcn_s_setprio(0);
    };

    // ---- unit scheduling: combined stream {w, w+4, ...}, A-prefix then B ----
    const int tot  = (33 - w + 3) >> 2;
    const int aCnt = (nA > w) ? ((nA - w + 3) >> 2) : 0;
    const int bCnt = tot - aCnt;

    // A pairs
    for (int i=0; i+1 < aCnt; i += 2)
        dual(oA, mA, lA, qA0, qA1, qrA, w + 4*i, w + 4*(i+1), nA);
    if (aCnt & 1)
        single(oA, mA, lA, qA0, qA1, qrA, w + 4*(aCnt-1), nA);
    // B pairs
    for (int j=0; j+1 < bCnt; j += 2)
        dual(oB, mB, lB, qB0, qB1, qrB, w + 4*(aCnt+j) - nA, w + 4*(aCnt+j+1) - nA, nB);
    if (bCnt & 1)
        single(oB, mB, lB, qB0, qB1, qrB, w + 4*(aCnt+bCnt-1) - nA, nB);

    // ---- merge 4 wave-partials per stripe ----
    #pragma unroll
    for (int dt=0;dt<4;++dt){
        *reinterpret_cast<f32x4*>(&Oorg[w][0][l15*64 + dt*16 + lg*4]) = oA[dt];
        *reinterpret_cast<f32x4*>(&Oorg[w][1][l15*64 + dt*16 + lg*4]) = oB[dt];
    }
    Lorg[w][0][l] = lA;
    Lorg[w][1][l] = lB;
    if (lg == 0){
        Morg[w][0][l15] = mA;
        Morg[w][1][l15] = mB;
    }
    __syncthreads();
    {
        const int h = tid>>7, q = (tid>>3)&15, d0 = (tid&7)*8;
        const float m0=Morg[0][h][q], m1=Morg[1][h][q], m2=Morg[2][h][q], m3=Morg[3][h][q];
        const float M = fmaxf(fmaxf(m0,m1), fmaxf(m2,m3));
        const float a0=exp2f(m0-M), a1=exp2f(m1-M), a2=exp2f(m2-M), a3=exp2f(m3-M);
        float L = 0.f;
        #pragma unroll
        for (int gg=0; gg<4; ++gg){
            L += a0*Lorg[0][h][gg*16+q] + a1*Lorg[1][h][gg*16+q]
               + a2*Lorg[2][h][gg*16+q] + a3*Lorg[3][h][gg*16+q];
        }
        const float inv = 1.0f / L;
        const int s = h ? sB : sA;
        float* op = out + batchoff + (size_t)(s*16 + q)*64 + d0;
        #pragma unroll
        for (int j=0;j<8;++j){
            const float v = a0*Oorg[0][h][q*64+d0+j] + a1*Oorg[1][h][q*64+d0+j]
                          + a2*Oorg[2][h][q*64+d0+j] + a3*Oorg[3][h][q*64+d0+j];
            op[j] = v * inv;
        }
    }
}

extern "C" void kernel_launch(void* const* d_in, const int* in_sizes, int n_in,
                              void* d_out, int out_size, void* d_ws, size_t ws_size,
                              hipStream_t stream) {
    const float* x  = (const float*)d_in[0];
    const float* Wq = (const float*)d_in[1];
    const float* Wk = (const float*)d_in[2];
    const float* Wv = (const float*)d_in[3];
    float* out = (float*)d_out;

    const size_t NTOK = (size_t)B_*T_*64;
    __hip_bfloat16* Wfrag = (__hip_bfloat16*)d_ws;
    __hip_bfloat16* Qfrag = Wfrag + (size_t)24576*8;
    __hip_bfloat16* Kfrag = Qfrag + NTOK;
    __hip_bfloat16* Vfrag = Kfrag + NTOK;

    wconv_kernel<<<96, 256, 0, stream>>>(Wq, Wk, Wv, Wfrag);
    proj_kernel<<<512, 384, 0, stream>>>(x, Wfrag, Qfrag, Kfrag, Vfrag);
    fattn_kernel<<<512, 256, 0, stream>>>(Qfrag, Kfrag, Vfrag, out);
}